// Round 16
// baseline (304.767 us; speedup 1.0000x reference)
//
#include <hip/hip_runtime.h>

#define NN 100000
#define NE 600000

typedef unsigned short u16;
typedef float f32x4 __attribute__((ext_vector_type(4)));
typedef short s16x8 __attribute__((ext_vector_type(8)));

__device__ inline u16 f2bf(float f) {            // fp32 -> bf16 RNE
    unsigned u = __float_as_uint(f);
    return (u16)((u + 0x7FFFu + ((u >> 16) & 1u)) >> 16);
}
__device__ inline float bflo(unsigned u) { return __uint_as_float(u << 16); }
__device__ inline float bfhi(unsigned u) { return __uint_as_float(u & 0xFFFF0000u); }
__device__ inline unsigned pk(float a, float b) {
    return (unsigned)f2bf(a) | ((unsigned)f2bf(b) << 16);
}

// ---------------- degree / padded-CSR build ----------------
// Adjacency lists are padded to multiples of 8 with sentinel NN (the zero row),
// so aggs need no predication and index loads vectorize (start is 32B-aligned).

__global__ void k_deg_count(const int* __restrict__ col, int* __restrict__ deg, int E) {
    int e = blockIdx.x * 256 + threadIdx.x;
    if (e < E) atomicAdd(&deg[col[e]], 1);
}

// scan over PADDED degree pd = ceil(deg/8)*8; dinv fused (no atomics —
// round-12 lesson: small-bin global atomic histograms serialize cross-XCD).
__global__ void k_scan1(const int* __restrict__ deg, int* __restrict__ offs,
                        int* __restrict__ bsums, float* __restrict__ dinv, int n) {
    __shared__ int s[256];
    int t = threadIdx.x;
    int i = blockIdx.x * 256 + t;
    int d = (i < n) ? deg[i] : 0;
    int v = (i < n) ? (((d + 7) >> 3) << 3) : 0;
    if (i < n) dinv[i] = rsqrtf((float)(d + 1));   // +1: self-loop
    s[t] = v;
    __syncthreads();
    for (int off = 1; off < 256; off <<= 1) {
        int x = (t >= off) ? s[t - off] : 0;
        __syncthreads();
        s[t] += x;
        __syncthreads();
    }
    if (i < n) offs[i] = s[t] - v;
    if (t == 255) bsums[blockIdx.x] = s[255];
}

__global__ void k_scan2(int* __restrict__ bsums, int nb) {
    __shared__ int s[512];
    int t = threadIdx.x;
    int v = (t < nb) ? bsums[t] : 0;
    s[t] = v;
    __syncthreads();
    for (int off = 1; off < 512; off <<= 1) {
        int x = (t >= off) ? s[t - off] : 0;
        __syncthreads();
        s[t] += x;
        __syncthreads();
    }
    if (t < nb) bsums[t] = s[t] - v;
}

__global__ void k_scan3(int* __restrict__ offs, const int* __restrict__ bsums,
                        int* __restrict__ cursor, int n) {
    int i = blockIdx.x * 256 + threadIdx.x;
    if (i < n) {
        int o = offs[i] + bsums[i >> 8];
        offs[i] = o;
        cursor[i] = o;
    }
}

__global__ void k_fill(const int* __restrict__ row, const int* __restrict__ col,
                       int* __restrict__ cursor, int* __restrict__ srcs, int E) {
    int e = blockIdx.x * 256 + threadIdx.x;
    if (e < E) {
        int p = atomicAdd(&cursor[col[e]], 1);
        srcs[p] = row[e];
    }
}

// fill padding slots [offs+deg, offs+pd) with sentinel NN (zero row)
__global__ void k_pad(const int* __restrict__ deg, const int* __restrict__ offs,
                      int* __restrict__ srcs, int n) {
    int i = blockIdx.x * 256 + threadIdx.x;
    if (i < n) {
        int d = deg[i];
        int pd = ((d + 7) >> 3) << 3;
        int o = offs[i] + d;
        for (int j = d; j < pd; j++) srcs[o++] = NN;
    }
}

// ---------------- W pack (all 3 weights, one launch) + bufA zero-row ---------
// Wp element ((t*4+kk)*64 + l)*8 + i  <-  W[kk*32 + (l>>4)*8 + i][t*16 + (l&15)]
// Zeroes bufA bytes [NN*256, NN*256+256): the zero row (index NN, 256B stride)
// gathered by padded sentinel slots. All G layouts use 256B row stride, so one
// sentinel works for relu (256B used) and softmax (first 128B used) alike.

__device__ inline void pack_one(const float* W, u16* Wp, int g, int DOUT) {
    int i  = g & 7;
    int l  = (g >> 3) & 63;
    int kk = (g >> 9) & 3;
    int t  = g >> 11;
    int k = kk * 32 + ((l >> 4) << 3) + i;
    int c = t * 16 + (l & 15);
    Wp[g] = f2bf(W[k * DOUT + c]);
}

__global__ __launch_bounds__(256)
void k_pack_all(const float* __restrict__ W1, const float* __restrict__ W2,
                const float* __restrict__ W3, u16* __restrict__ wp1,
                u16* __restrict__ wp2, u16* __restrict__ wp3,
                uint4* __restrict__ bufA) {
    int gid = blockIdx.x * 256 + threadIdx.x;
    if (gid < 16384) pack_one(W1, wp1, gid, 128);
    else if (gid < 32768) pack_one(W2, wp2, gid - 16384, 128);
    else if (gid < 40960) pack_one(W3, wp3, gid - 32768, 64);
    else if (gid < 40976) bufA[(size_t)NN * 16 + (gid - 40960)] = make_uint4(0, 0, 0, 0);
}

// ---------------- GEMM: G = (H @ W) * dinv[row], bf16 MFMA, LDS-free ---------
// Block = 4 waves x 32 rows = 128 rows; each wave's 2 row-groups share B-frags.
// G row stride is ALWAYS 128 u16 (256B), regardless of DOUT (64-wide layer
// uses the first half of each row) — lets all aggs share one zero row.
// A-frag (16x16x32): lane l holds A[l&15][(l>>4)*8 + i].
// D: col=l&15, row=(l>>4)*4+reg  (guide §3, m89-verified).

template <int DOUT, bool OB16, bool AF32>
__global__ __launch_bounds__(256)
void k_gemm_mfma(const void* __restrict__ Hin, const u16* __restrict__ Wp,
                 const float* __restrict__ dinv, void* __restrict__ Gout, int n) {
    constexpr int NT = DOUT / 16;
    int tid = threadIdx.x;
    int w = tid >> 6, l = tid & 63;
    int r0 = blockIdx.x * 128 + w * 32;
    int arow0 = r0 + (l & 15);
    int arow1 = arow0 + 16;
    bool av0 = arow0 < n, av1 = arow1 < n;
    const s16x8* A0 = (const s16x8*)((const u16*)Hin + (size_t)arow0 * 128);
    const s16x8* A1 = (const s16x8*)((const u16*)Hin + (size_t)arow1 * 128);
    const float* A032 = (const float*)Hin + (size_t)arow0 * 128;
    const float* A132 = (const float*)Hin + (size_t)arow1 * 128;
    const s16x8* Wp8 = (const s16x8*)Wp;
    const s16x8 zero = {0, 0, 0, 0, 0, 0, 0, 0};

    f32x4 acc0[NT], acc1[NT];
#pragma unroll
    for (int t = 0; t < NT; t++) { acc0[t] = {0.f,0.f,0.f,0.f}; acc1[t] = {0.f,0.f,0.f,0.f}; }

#pragma unroll
    for (int kk = 0; kk < 4; kk++) {                 // K = 128 = 4 x 32
        s16x8 a0, a1;
        if (AF32) {
            a0 = zero; a1 = zero;
            if (av0) {
                const f32x4* p = (const f32x4*)(A032 + kk * 32 + ((l >> 4) << 3));
                f32x4 f0 = p[0], f1 = p[1];
                a0[0]=(short)f2bf(f0[0]); a0[1]=(short)f2bf(f0[1]);
                a0[2]=(short)f2bf(f0[2]); a0[3]=(short)f2bf(f0[3]);
                a0[4]=(short)f2bf(f1[0]); a0[5]=(short)f2bf(f1[1]);
                a0[6]=(short)f2bf(f1[2]); a0[7]=(short)f2bf(f1[3]);
            }
            if (av1) {
                const f32x4* p = (const f32x4*)(A132 + kk * 32 + ((l >> 4) << 3));
                f32x4 f0 = p[0], f1 = p[1];
                a1[0]=(short)f2bf(f0[0]); a1[1]=(short)f2bf(f0[1]);
                a1[2]=(short)f2bf(f0[2]); a1[3]=(short)f2bf(f0[3]);
                a1[4]=(short)f2bf(f1[0]); a1[5]=(short)f2bf(f1[1]);
                a1[6]=(short)f2bf(f1[2]); a1[7]=(short)f2bf(f1[3]);
            }
        } else {
            a0 = av0 ? A0[kk * 4 + (l >> 4)] : zero;
            a1 = av1 ? A1[kk * 4 + (l >> 4)] : zero;
        }
#pragma unroll
        for (int t = 0; t < NT; t++) {
            s16x8 b = Wp8[(t * 4 + kk) * 64 + l];
            acc0[t] = __builtin_amdgcn_mfma_f32_16x16x32_bf16(a0, b, acc0[t], 0, 0, 0);
            acc1[t] = __builtin_amdgcn_mfma_f32_16x16x32_bf16(a1, b, acc1[t], 0, 0, 0);
        }
    }

    int col = l & 15;
#pragma unroll
    for (int r = 0; r < 4; r++) {
        int gr0 = r0 + (l >> 4) * 4 + r;
        if (gr0 < n) {
            float di = dinv[gr0];
#pragma unroll
            for (int t = 0; t < NT; t++) {
                float v = acc0[t][r] * di;
                if (OB16) ((u16*)Gout)[(size_t)gr0 * 128 + t * 16 + col] = f2bf(v);
                else      ((float*)Gout)[(size_t)gr0 * 128 + t * 16 + col] = v;
            }
        }
        int gr1 = gr0 + 16;
        if (gr1 < n) {
            float di = dinv[gr1];
#pragma unroll
            for (int t = 0; t < NT; t++) {
                float v = acc1[t][r] * di;
                if (OB16) ((u16*)Gout)[(size_t)gr1 * 128 + t * 16 + col] = f2bf(v);
                else      ((float*)Gout)[(size_t)gr1 * 128 + t * 16 + col] = v;
            }
        }
    }
}

// ---------------- aggregation (gather) ----------------
// 4 nodes per wave (16-lane groups). Padded CSR: every batch is a full 8
// independent gathers (sentinel slots hit the zero row; adds are exact no-ops).
// No predication; indices load as two int4 (start is 32B-aligned by padding).

#define ACC8(A, U) \
    A[0] += bflo(U.x); A[1] += bfhi(U.x); A[2] += bflo(U.y); A[3] += bfhi(U.y); \
    A[4] += bflo(U.z); A[5] += bfhi(U.z); A[6] += bflo(U.w); A[7] += bfhi(U.w);

__global__ __launch_bounds__(256)
void k_agg_relu(const uint4* __restrict__ G, const int* __restrict__ offs,
                const int* __restrict__ deg, const int* __restrict__ srcs,
                const float* __restrict__ dinv, const float* __restrict__ bias,
                uint4* __restrict__ out, int n) {
    int t = blockIdx.x * 256 + threadIdx.x;
    int wv = t >> 6;
    int lane = t & 63;
    int hl = lane & 15;                 // lane within 16-lane group
    int node = wv * 4 + (lane >> 4);    // 4 nodes per wave
    if (node >= n) return;

    uint4 us = G[(size_t)node * 16 + hl];          // self-loop
    float a0[8], a1[8], a2[8], a3[8];
    a0[0] = bflo(us.x); a0[1] = bfhi(us.x); a0[2] = bflo(us.y); a0[3] = bfhi(us.y);
    a0[4] = bflo(us.z); a0[5] = bfhi(us.z); a0[6] = bflo(us.w); a0[7] = bfhi(us.w);
#pragma unroll
    for (int i = 0; i < 8; i++) { a1[i] = 0.f; a2[i] = 0.f; a3[i] = 0.f; }

    int start = offs[node];
    int nb = (deg[node] + 7) >> 3;
    for (int b = 0; b < nb; b++) {
        const int4* ip = (const int4*)&srcs[start + b * 8];
        int4 i0 = ip[0], i1 = ip[1];
        uint4 u0 = G[(size_t)i0.x * 16 + hl];
        uint4 u1 = G[(size_t)i0.y * 16 + hl];
        uint4 u2 = G[(size_t)i0.z * 16 + hl];
        uint4 u3 = G[(size_t)i0.w * 16 + hl];
        uint4 u4 = G[(size_t)i1.x * 16 + hl];
        uint4 u5 = G[(size_t)i1.y * 16 + hl];
        uint4 u6 = G[(size_t)i1.z * 16 + hl];
        uint4 u7 = G[(size_t)i1.w * 16 + hl];
        ACC8(a0, u0) ACC8(a1, u1) ACC8(a2, u2) ACC8(a3, u3)
        ACC8(a0, u4) ACC8(a1, u5) ACC8(a2, u6) ACC8(a3, u7)
    }

    float di = dinv[node];
    const float4* b8 = (const float4*)bias;
    float4 b0 = b8[hl * 2], b1 = b8[hl * 2 + 1];
    float bb[8] = {b0.x, b0.y, b0.z, b0.w, b1.x, b1.y, b1.z, b1.w};
    float r[8];
#pragma unroll
    for (int i = 0; i < 8; i++) {
        float s = (a0[i] + a1[i]) + (a2[i] + a3[i]);
        r[i] = fmaxf(fmaf(s, di, bb[i]), 0.f);
    }
    out[(size_t)node * 16 + hl] =
        make_uint4(pk(r[0], r[1]), pk(r[2], r[3]), pk(r[4], r[5]), pk(r[6], r[7]));
}

#define ACC4(A, U) \
    A[0] += bflo(U.x); A[1] += bfhi(U.x); A[2] += bflo(U.y); A[3] += bfhi(U.y);

// final layer: G bf16, 256B row stride, first 128B used (cols 0..63).
// 4 nodes/wave, 4 features/lane; log_softmax via 4-wide local + 4 shfl_xor.
__global__ __launch_bounds__(256)
void k_agg_softmax(const uint2* __restrict__ G, const int* __restrict__ offs,
                   const int* __restrict__ deg, const int* __restrict__ srcs,
                   const float* __restrict__ dinv, const float* __restrict__ bias,
                   float4* __restrict__ out, int n) {
    int t = blockIdx.x * 256 + threadIdx.x;
    int wv = t >> 6;
    int lane = t & 63;
    int hl = lane & 15;
    int node = wv * 4 + (lane >> 4);
    if (node >= n) return;

    uint2 us = G[(size_t)node * 32 + hl];          // self-loop (256B stride)
    float a0[4], a1[4], a2[4], a3[4];
    a0[0] = bflo(us.x); a0[1] = bfhi(us.x); a0[2] = bflo(us.y); a0[3] = bfhi(us.y);
#pragma unroll
    for (int i = 0; i < 4; i++) { a1[i] = 0.f; a2[i] = 0.f; a3[i] = 0.f; }

    int start = offs[node];
    int nb = (deg[node] + 7) >> 3;
    for (int b = 0; b < nb; b++) {
        const int4* ip = (const int4*)&srcs[start + b * 8];
        int4 i0 = ip[0], i1 = ip[1];
        uint2 u0 = G[(size_t)i0.x * 32 + hl];
        uint2 u1 = G[(size_t)i0.y * 32 + hl];
        uint2 u2 = G[(size_t)i0.z * 32 + hl];
        uint2 u3 = G[(size_t)i0.w * 32 + hl];
        uint2 u4 = G[(size_t)i1.x * 32 + hl];
        uint2 u5 = G[(size_t)i1.y * 32 + hl];
        uint2 u6 = G[(size_t)i1.z * 32 + hl];
        uint2 u7 = G[(size_t)i1.w * 32 + hl];
        ACC4(a0, u0) ACC4(a1, u1) ACC4(a2, u2) ACC4(a3, u3)
        ACC4(a0, u4) ACC4(a1, u5) ACC4(a2, u6) ACC4(a3, u7)
    }

    float di = dinv[node];
    float4 bb = ((const float4*)bias)[hl];
    float t0 = fmaf((a0[0] + a1[0]) + (a2[0] + a3[0]), di, bb.x);
    float t1 = fmaf((a0[1] + a1[1]) + (a2[1] + a3[1]), di, bb.y);
    float t2 = fmaf((a0[2] + a1[2]) + (a2[2] + a3[2]), di, bb.z);
    float t3 = fmaf((a0[3] + a1[3]) + (a2[3] + a3[3]), di, bb.w);
    float m = fmaxf(fmaxf(t0, t1), fmaxf(t2, t3));
#pragma unroll
    for (int off = 1; off < 16; off <<= 1) m = fmaxf(m, __shfl_xor(m, off, 64));
    float e = expf(t0 - m) + expf(t1 - m) + expf(t2 - m) + expf(t3 - m);
#pragma unroll
    for (int off = 1; off < 16; off <<= 1) e += __shfl_xor(e, off, 64);
    float lse = m + logf(e);
    out[(size_t)node * 16 + hl] = make_float4(t0 - lse, t1 - lse, t2 - lse, t3 - lse);
}

// ---------------- launch ----------------

extern "C" void kernel_launch(void* const* d_in, const int* in_sizes, int n_in,
                              void* d_out, int out_size, void* d_ws, size_t ws_size,
                              hipStream_t stream) {
    const float* x  = (const float*)d_in[0];
    const int*   ei = (const int*)d_in[1];
    const int*   row = ei;             // edge_index[0]: source
    const int*   col = ei + NE;        // edge_index[1]: destination
    const float* W1 = (const float*)d_in[2];
    const float* b1 = (const float*)d_in[3];
    const float* W2 = (const float*)d_in[4];
    const float* b2 = (const float*)d_in[5];
    const float* W3 = (const float*)d_in[6];
    const float* b3 = (const float*)d_in[7];
    float* outp = (float*)d_out;

    char* ws = (char*)d_ws;
    size_t off = 0;
    auto alloc = [&](size_t bytes) -> void* {
        void* p = (void*)(ws + off);
        off += (bytes + 255) & ~(size_t)255;
        return p;
    };
    float* dinv  = (float*)alloc((size_t)NN * 4);
    float* bufA  = (float*)alloc((size_t)NN * 128 * 4);   // bf16 G (256B rows) + zero row
    u16*   bufB  = (u16*)alloc((size_t)NN * 128 * 2);     // bf16 H (layers 2,3)
    int*   deg   = (int*)alloc((size_t)NN * 4);
    int*   offs  = (int*)alloc((size_t)NN * 4);
    int*   cursor= (int*)alloc((size_t)NN * 4);
    int*   bsums = (int*)alloc(1024 * 4);
    int*   srcs  = (int*)alloc(((size_t)NE + 7 * (size_t)NN + 8) * 4);  // padded CSR
    u16*   wp1   = (u16*)alloc(128 * 128 * 2);
    u16*   wp2   = (u16*)alloc(128 * 128 * 2);
    u16*   wp3   = (u16*)alloc(128 * 64 * 2);

    int nbN = (NN + 255) / 256;   // 391
    int nbE = (NE + 255) / 256;

    hipMemsetAsync(deg, 0, (size_t)NN * 4, stream);
    k_deg_count<<<nbE, 256, 0, stream>>>(col, deg, NE);
    k_scan1    <<<nbN, 256, 0, stream>>>(deg, offs, bsums, dinv, NN);
    k_scan2    <<<1,   512, 0, stream>>>(bsums, nbN);
    k_scan3    <<<nbN, 256, 0, stream>>>(offs, bsums, cursor, NN);
    k_fill     <<<nbE, 256, 0, stream>>>(row, col, cursor, srcs, NE);
    k_pad      <<<nbN, 256, 0, stream>>>(deg, offs, srcs, NN);
    k_pack_all <<<161, 256, 0, stream>>>(W1, W2, W3, wp1, wp2, wp3, (uint4*)bufA);

    int gb = (NN + 127) / 128;                  // 782 (128 rows/block)
    int ab4 = ((NN + 3) / 4 * 64 + 255) / 256;  // 4 nodes/wave -> 6250 blocks

    // layer 1: x(fp32, inline cvt) -> bufA(bf16 G) -> bufB(bf16 h1)
    k_gemm_mfma<128, true, true><<<gb, 256, 0, stream>>>(x, wp1, dinv, bufA, NN);
    k_agg_relu <<<ab4, 256, 0, stream>>>((uint4*)bufA, offs, deg, srcs, dinv, b1, (uint4*)bufB, NN);
    // layer 2: bufB -> bufA(bf16 G) -> bufB(bf16 h2)
    k_gemm_mfma<128, true, false><<<gb, 256, 0, stream>>>(bufB, wp2, dinv, bufA, NN);
    k_agg_relu <<<ab4, 256, 0, stream>>>((uint4*)bufA, offs, deg, srcs, dinv, b2, (uint4*)bufB, NN);
    // layer 3: bufB -> bufA(bf16 G, 64 cols in 256B rows) -> out (log_softmax)
    k_gemm_mfma<64, true, false><<<gb, 256, 0, stream>>>(bufB, wp3, dinv, bufA, NN);
    k_agg_softmax<<<ab4, 256, 0, stream>>>((uint2*)bufA, offs, deg, srcs, dinv, b3, (float4*)outp, NN);
}